// Round 3
// baseline (585.066 us; speedup 1.0000x reference)
//
#include <hip/hip_runtime.h>
#include <hip/hip_bf16.h>

// GCN 3-layer GraphConv, R3:
//  - graph build WITHOUT global data atomics: bucket partition (128 dst/bucket)
//    via per-chunk LDS hist -> scan -> LDS-cursor scatter of packed records
//  - outdeg via range-partitioned multi-pass LDS histogram -> srcn
//  - aggregation per (bucket, quarter): LDS counting-sort by dstlow, then
//    16-lane-group register gather-accumulate (dstn computed in-block)
//  - GEMMs via mfma_f32_16x16x32_bf16 (unchanged from R2, verified)

constexpr int BLK = 256;
constexpr int CH = 32768;    // edges per partition chunk-block
constexpr int RB = 16384;    // src-histogram bins per range (64KB LDS)

typedef __attribute__((ext_vector_type(8))) short s8v;
typedef __attribute__((ext_vector_type(4))) float f4v;

__device__ __forceinline__ float bflo(unsigned int u) { return __uint_as_float(u << 16); }
__device__ __forceinline__ float bfhi(unsigned int u) { return __uint_as_float(u & 0xffff0000u); }
__device__ __forceinline__ unsigned int bfr(float f) {
    unsigned int u = __float_as_uint(f);
    return (u + 0x7fffu + ((u >> 16) & 1u)) >> 16;
}
__device__ __forceinline__ unsigned int bfpack(float lo, float hi) {
    unsigned int ul = __float_as_uint(lo), uh = __float_as_uint(hi);
    unsigned int rl = (ul + 0x7fffu + ((ul >> 16) & 1u)) >> 16;
    unsigned int rh = (uh + 0x7fffu + ((uh >> 16) & 1u)) & 0xffff0000u;
    return rl | rh;
}

// ---------------- partition by dst bucket (dst>>7) ----------------
__global__ __launch_bounds__(256) void k_pcount(const int* __restrict__ dst, int* __restrict__ pmat,
                                                int E, int NB) {
    __shared__ int h[1024];
    for (int i = threadIdx.x; i < NB; i += 256) h[i] = 0;
    __syncthreads();
    int b = blockIdx.x;
    int e0 = b * CH, e1 = min(e0 + CH, E);
    for (int e = e0 + threadIdx.x; e < e1; e += 256) atomicAdd(&h[dst[e] >> 7], 1);
    __syncthreads();
    for (int i = threadIdx.x; i < NB; i += 256) pmat[(size_t)b * NB + i] = h[i];
}

__global__ __launch_bounds__(1024) void k_pscan(const int* __restrict__ pmat, int* __restrict__ omat,
                                                int* __restrict__ bbase, int NB, int nblk) {
    __shared__ int s[1024];
    int t = threadIdx.x;
    int tot = 0;
    if (t < NB)
        for (int b = 0; b < nblk; b++) tot += pmat[(size_t)b * NB + t];
    s[t] = (t < NB) ? tot : 0;
    __syncthreads();
    for (int d = 1; d < 1024; d <<= 1) {
        int x = (t >= d) ? s[t - d] : 0;
        __syncthreads();
        s[t] += x;
        __syncthreads();
    }
    if (t < NB) {
        int base = (t > 0) ? s[t - 1] : 0;
        bbase[t] = base;
        int run = base;
        for (int b = 0; b < nblk; b++) { omat[(size_t)b * NB + t] = run; run += pmat[(size_t)b * NB + t]; }
        if (t == NB - 1) bbase[NB] = run;   // == E
    }
}

__global__ __launch_bounds__(256) void k_pscatter(const int* __restrict__ src, const int* __restrict__ dst,
                                                  const int* __restrict__ omat, unsigned int* __restrict__ ebuf,
                                                  int E, int NB) {
    __shared__ int cur[1024];
    int b = blockIdx.x;
    for (int i = threadIdx.x; i < NB; i += 256) cur[i] = omat[(size_t)b * NB + i];
    __syncthreads();
    int e0 = b * CH, e1 = min(e0 + CH, E);
    for (int e = e0 + threadIdx.x; e < e1; e += 256) {
        int d = dst[e];
        int k = d >> 7;
        int slot = atomicAdd(&cur[k], 1);
        ebuf[slot] = (unsigned)src[e] | ((unsigned)(d & 127) << 17);
    }
}

// ---------------- outdeg histogram (range-partitioned, LDS) -> srcn ----------------
__global__ __launch_bounds__(256) void k_shist(const int* __restrict__ src, int* __restrict__ part,
                                               int E, int CHE) {
    __shared__ int h[RB];
    for (int i = threadIdx.x; i < RB; i += 256) h[i] = 0;
    __syncthreads();
    int r = blockIdx.x >> 4, c = blockIdx.x & 15;
    int e0 = c * CHE, e1 = min(e0 + CHE, E);
    for (int e = e0 + threadIdx.x; e < e1; e += 256) {
        int s = src[e];
        if ((s >> 14) == r) atomicAdd(&h[s & (RB - 1)], 1);
    }
    __syncthreads();
    size_t off = (size_t)blockIdx.x * RB;
    for (int i = threadIdx.x; i < RB; i += 256) part[off + i] = h[i];
}

__global__ __launch_bounds__(256) void k_sreduce(const int* __restrict__ part, float* __restrict__ srcn, int N) {
    int n = blockIdx.x * 256 + threadIdx.x;
    if (n >= N) return;
    int r = n >> 14, b = n & (RB - 1);
    int s = 0;
    for (int c = 0; c < 16; c++) s += part[((size_t)(r * 16 + c)) * RB + b];
    if (s < 1) s = 1;
    srcn[n] = rsqrtf((float)s);
}

// ---------------- weight transpose + bf16 ----------------
__global__ void k_wt(const float* __restrict__ W, unsigned short* __restrict__ Wt, int total) {
    int i = blockIdx.x * blockDim.x + threadIdx.x;
    if (i < total) {
        int c = i >> 7, k = i & 127;
        int Ncol = total >> 7;
        Wt[i] = (unsigned short)bfr(W[k * Ncol + c]);
    }
}

// ---------------- A0 = bf16(features * srcn) ----------------
__global__ void k_prep(const float* __restrict__ F, const float* __restrict__ srcn,
                       unsigned short* __restrict__ A0, int N) {
    int i = blockIdx.x * blockDim.x + threadIdx.x;
    if (i >= N * 16) return;
    int row = i >> 4;
    float s = srcn[row];
    const float4* p = (const float4*)(F + (size_t)i * 8);
    float4 a = p[0], b = p[1];
    uint4 o;
    o.x = bfpack(a.x * s, a.y * s);
    o.y = bfpack(a.z * s, a.w * s);
    o.z = bfpack(b.x * s, b.y * s);
    o.w = bfpack(b.z * s, b.w * s);
    *(uint4*)(A0 + (size_t)i * 8) = o;
}

// ---------------- MFMA GEMM (unchanged from R2) ----------------
template <int NT, int EPI>
__global__ __launch_bounds__(256) void k_gemm_mfma(const unsigned short* __restrict__ A,
                                                   const unsigned short* __restrict__ Wt,
                                                   const float* __restrict__ bias,
                                                   unsigned short* __restrict__ outb,
                                                   float* __restrict__ outf, int M) {
    __shared__ unsigned short As[64 * 128];
    __shared__ unsigned short Ws[NT * 16 * 128];
    int tx = threadIdx.x;
    int row0 = blockIdx.x * 64;
    for (int p = 0; p < NT; ++p) {
        int r = p * 16 + (tx >> 4);
        int c = tx & 15;
        int cs = c ^ (r & 7);
        *(uint4*)(&Ws[(r * 16 + cs) * 8]) = *(const uint4*)(Wt + (size_t)r * 128 + c * 8);
    }
    for (int p = 0; p < 4; ++p) {
        int r = p * 16 + (tx >> 4);
        int c = tx & 15;
        int cs = c ^ (r & 7);
        int gr = row0 + r;
        uint4 v = make_uint4(0u, 0u, 0u, 0u);
        if (gr < M) v = *(const uint4*)(A + (size_t)gr * 128 + c * 8);
        *(uint4*)(&As[(r * 16 + cs) * 8]) = v;
    }
    __syncthreads();

    int w = tx >> 6, l = tx & 63;
    int lr = l & 15, lg = l >> 4;
    f4v acc[NT];
#pragma unroll
    for (int nt = 0; nt < NT; ++nt) { acc[nt][0] = 0.f; acc[nt][1] = 0.f; acc[nt][2] = 0.f; acc[nt][3] = 0.f; }

    int ar = w * 16 + lr;
#pragma unroll
    for (int kk = 0; kk < 4; ++kk) {
        s8v af = *(const s8v*)(&As[(ar * 16 + ((kk * 4 + lg) ^ (ar & 7))) * 8]);
#pragma unroll
        for (int nt = 0; nt < NT; ++nt) {
            int br = nt * 16 + lr;
            s8v bf = *(const s8v*)(&Ws[(br * 16 + ((kk * 4 + lg) ^ (br & 7))) * 8]);
            acc[nt] = __builtin_amdgcn_mfma_f32_16x16x32_bf16(af, bf, acc[nt], 0, 0, 0);
        }
    }
#pragma unroll
    for (int nt = 0; nt < NT; ++nt) {
#pragma unroll
        for (int i = 0; i < 4; ++i) {
            int R = row0 + w * 16 + lg * 4 + i;
            if (R < M) {
                int col = nt * 16 + lr;
                float v = acc[nt][i];
                if (EPI == 0) {
                    outb[(size_t)R * 128 + col] = (unsigned short)bfr(v);
                } else {
                    v += bias[col];
                    v = 1.f / (1.f + __expf(-v)) + 1e-8f;
                    outf[(size_t)R * 16 + col] = v;
                }
            }
        }
    }
}

// ---------------- bucketed aggregation ----------------
// block = (bucket k, quarter q): counting-sort bucket records by dstlow in LDS,
// then 16 groups x 16 lanes gather-accumulate; 2 nodes per group.
// EPI 0: out = bf16(relu(sum*dstn + bias) * srcn); EPI 1: out = bf16(sum*dstn)
template <int EPI>
__global__ __launch_bounds__(256) void k_bagg(const unsigned short* __restrict__ hw,
                                              const unsigned int* __restrict__ ebuf,
                                              const int* __restrict__ bbase,
                                              const float* __restrict__ srcn,
                                              const float* __restrict__ bias,
                                              unsigned short* __restrict__ out, int N) {
    __shared__ unsigned int rec[4096];
    __shared__ unsigned int sorted[2048];
    __shared__ int cnt[128];
    __shared__ int wstart[33];
    __shared__ int wcur[32];
    int k = blockIdx.x >> 2, q = blockIdx.x & 3;
    int tx = threadIdx.x;
    int ebeg = bbase[k];
    int ecnt = bbase[k + 1] - ebeg;
    if (ecnt > 4096) ecnt = 4096;   // never triggers (Poisson ~1563)
    if (tx < 128) cnt[tx] = 0;
    __syncthreads();
    for (int i = tx; i < ecnt; i += 256) {
        unsigned int r = ebuf[ebeg + i];
        rec[i] = r;
        atomicAdd(&cnt[(r >> 17) & 127], 1);
    }
    __syncthreads();
    int w0 = q * 32;
    if (tx == 0) {
        int run = 0;
        for (int j = 0; j < 32; j++) { wstart[j] = run; wcur[j] = run; run += cnt[w0 + j]; }
        wstart[32] = run;
    }
    __syncthreads();
    for (int i = tx; i < ecnt; i += 256) {
        unsigned int r = rec[i];
        int dl = (r >> 17) & 127;
        if (dl >= w0 && dl < w0 + 32) {
            int p = atomicAdd(&wcur[dl - w0], 1);
            if (p < 2048) sorted[p] = r & 0x1FFFFu;
        }
    }
    __syncthreads();

    int wave = tx >> 6, lane = tx & 63, grp = lane >> 4, sub = lane & 15;
    int gid = wave * 4 + grp;
#pragma unroll
    for (int rep = 0; rep < 2; rep++) {
        int j = gid + rep * 16;
        int v = k * 128 + w0 + j;
        if (v >= N) continue;
        int s0 = wstart[j], s1 = wstart[j + 1];
        if (s0 > 2048) s0 = 2048;
        if (s1 > 2048) s1 = 2048;

        float a0 = 0.f, a1 = 0.f, a2 = 0.f, a3 = 0.f, a4 = 0.f, a5 = 0.f, a6 = 0.f, a7 = 0.f;
#define ACC8(V)                                                         \
        a0 += bflo(V.x); a1 += bfhi(V.x); a2 += bflo(V.y); a3 += bfhi(V.y); \
        a4 += bflo(V.z); a5 += bfhi(V.z); a6 += bflo(V.w); a7 += bfhi(V.w);
        int e = s0;
        for (; e + 4 <= s1; e += 4) {
            int x0 = sorted[e], x1 = sorted[e + 1], x2 = sorted[e + 2], x3 = sorted[e + 3];
            uint4 v0 = *(const uint4*)(hw + (size_t)x0 * 128 + sub * 8);
            uint4 v1 = *(const uint4*)(hw + (size_t)x1 * 128 + sub * 8);
            uint4 v2 = *(const uint4*)(hw + (size_t)x2 * 128 + sub * 8);
            uint4 v3 = *(const uint4*)(hw + (size_t)x3 * 128 + sub * 8);
            ACC8(v0) ACC8(v1) ACC8(v2) ACC8(v3)
        }
        for (; e < s1; ++e) {
            int x0 = sorted[e];
            uint4 v0 = *(const uint4*)(hw + (size_t)x0 * 128 + sub * 8);
            ACC8(v0)
        }
#undef ACC8
        int deg = cnt[w0 + j];
        if (deg < 1) deg = 1;
        float dn = rsqrtf((float)deg);
        float o0 = a0 * dn, o1 = a1 * dn, o2 = a2 * dn, o3 = a3 * dn;
        float o4 = a4 * dn, o5 = a5 * dn, o6 = a6 * dn, o7 = a7 * dn;
        if (EPI == 0) {
            float4 b0 = *(const float4*)(bias + sub * 8);
            float4 b1 = *(const float4*)(bias + sub * 8 + 4);
            float sn = srcn[v];
            o0 = fmaxf(o0 + b0.x, 0.f) * sn; o1 = fmaxf(o1 + b0.y, 0.f) * sn;
            o2 = fmaxf(o2 + b0.z, 0.f) * sn; o3 = fmaxf(o3 + b0.w, 0.f) * sn;
            o4 = fmaxf(o4 + b1.x, 0.f) * sn; o5 = fmaxf(o5 + b1.y, 0.f) * sn;
            o6 = fmaxf(o6 + b1.z, 0.f) * sn; o7 = fmaxf(o7 + b1.w, 0.f) * sn;
        }
        uint4 o;
        o.x = bfpack(o0, o1); o.y = bfpack(o2, o3);
        o.z = bfpack(o4, o5); o.w = bfpack(o6, o7);
        *(uint4*)(out + (size_t)v * 128 + sub * 8) = o;
    }
}

extern "C" void kernel_launch(void* const* d_in, const int* in_sizes, int n_in,
                              void* d_out, int out_size, void* d_ws, size_t ws_size,
                              hipStream_t stream) {
    const float* features = (const float*)d_in[0];
    const int*   src      = (const int*)d_in[1];
    const int*   dst      = (const int*)d_in[2];
    const float* W0       = (const float*)d_in[3];
    const float* b0       = (const float*)d_in[4];
    const float* W1       = (const float*)d_in[5];
    const float* b1       = (const float*)d_in[6];
    const float* W2       = (const float*)d_in[7];
    const float* b2       = (const float*)d_in[8];
    float* out = (float*)d_out;

    const int N = in_sizes[0] / 128;
    const int E = in_sizes[1];
    const int NB = (N + 127) >> 7;            // 782 buckets
    const int nblk = (E + CH - 1) / CH;       // 49 partition chunks
    const int nrng = (N + RB - 1) / RB;       // 7 src-hist ranges
    const int CHE = (E + 15) / 16;

    char* ws = (char*)d_ws;
    size_t off = 0;
    auto alloc = [&](size_t bytes) -> char* {
        char* p = ws + off;
        off += (bytes + 255) / 256 * 256;
        return p;
    };
    int*   pmat  = (int*)alloc((size_t)nblk * NB * 4);
    int*   omat  = (int*)alloc((size_t)nblk * NB * 4);
    int*   bbase = (int*)alloc((size_t)(NB + 1) * 4);
    unsigned int* ebuf = (unsigned int*)alloc((size_t)E * 4);
    int*   spart = (int*)alloc((size_t)nrng * 16 * RB * 4);
    float* srcn  = (float*)alloc((size_t)N * 4);
    unsigned short* Wt0 = (unsigned short*)alloc(128 * 128 * 2);
    unsigned short* Wt1 = (unsigned short*)alloc(128 * 128 * 2);
    unsigned short* Wt2 = (unsigned short*)alloc(16 * 128 * 2);
    unsigned short* B1 = (unsigned short*)alloc((size_t)N * 128 * 2);
    unsigned short* B2 = (unsigned short*)alloc((size_t)N * 128 * 2);
    unsigned short* B3 = (unsigned short*)alloc((size_t)N * 128 * 2);
    (void)ws_size; (void)n_in; (void)out_size;

    // graph build (no global data atomics)
    k_pcount<<<nblk, 256, 0, stream>>>(dst, pmat, E, NB);
    k_pscan<<<1, 1024, 0, stream>>>(pmat, omat, bbase, NB, nblk);
    k_pscatter<<<nblk, 256, 0, stream>>>(src, dst, omat, ebuf, E, NB);
    k_shist<<<nrng * 16, 256, 0, stream>>>(src, spart, E, CHE);
    k_sreduce<<<(N + 255) / 256, 256, 0, stream>>>(spart, srcn, N);

    // weights + input prep
    k_wt<<<64, BLK, 0, stream>>>(W0, Wt0, 128 * 128);
    k_wt<<<64, BLK, 0, stream>>>(W1, Wt1, 128 * 128);
    k_wt<<<8, BLK, 0, stream>>>(W2, Wt2, 16 * 128);
    k_prep<<<(N * 16 + BLK - 1) / BLK, BLK, 0, stream>>>(features, srcn, B1, N);

    int gb = (N + 63) / 64;
    int ab = NB * 4;

    // layer 0
    k_gemm_mfma<8, 0><<<gb, 256, 0, stream>>>(B1, Wt0, nullptr, B2, nullptr, N);
    k_bagg<0><<<ab, 256, 0, stream>>>(B2, ebuf, bbase, srcn, b0, B3, N);
    // layer 1
    k_gemm_mfma<8, 0><<<gb, 256, 0, stream>>>(B3, Wt1, nullptr, B2, nullptr, N);
    k_bagg<0><<<ab, 256, 0, stream>>>(B2, ebuf, bbase, srcn, b1, B1, N);
    // layer 2: aggregate first (linearity), then 128->16 GEMM with bias+sigmoid
    k_bagg<1><<<ab, 256, 0, stream>>>(B1, ebuf, bbase, nullptr, nullptr, B3, N);
    k_gemm_mfma<1, 1><<<gb, 256, 0, stream>>>(B3, Wt2, b2, nullptr, out, N);
}

// Round 4
// 406.355 us; speedup vs baseline: 1.4398x; 1.4398x over previous
//
#include <hip/hip_runtime.h>
#include <hip/hip_bf16.h>

// GCN 3-layer GraphConv, R4:
//  - dual bucket partition (dst-bucket records + src-bucket count bytes) in ONE
//    edge pass; 196 chunk-blocks; two-phase parallel scan (no single-block serial)
//  - srcn from per-src-bucket LDS histogram of scattered srclow bytes (k_shist gone)
//  - k_bagg: FULL bucket per block (records loaded+sorted once, not 4x);
//    parallel 128-bin scan; 16 groups x 8 nodes gather-accumulate
//  - GEMMs via mfma_f32_16x16x32_bf16 (unchanged, verified since R2)

constexpr int BLK = 256;
constexpr int CH = 8192;     // edges per partition chunk-block -> 196 blocks

typedef __attribute__((ext_vector_type(8))) short s8v;
typedef __attribute__((ext_vector_type(4))) float f4v;

__device__ __forceinline__ float bflo(unsigned int u) { return __uint_as_float(u << 16); }
__device__ __forceinline__ float bfhi(unsigned int u) { return __uint_as_float(u & 0xffff0000u); }
__device__ __forceinline__ unsigned int bfr(float f) {
    unsigned int u = __float_as_uint(f);
    return (u + 0x7fffu + ((u >> 16) & 1u)) >> 16;
}
__device__ __forceinline__ unsigned int bfpack(float lo, float hi) {
    unsigned int ul = __float_as_uint(lo), uh = __float_as_uint(hi);
    unsigned int rl = (ul + 0x7fffu + ((ul >> 16) & 1u)) >> 16;
    unsigned int rh = (uh + 0x7fffu + ((uh >> 16) & 1u)) & 0xffff0000u;
    return rl | rh;
}

// ---------------- dual partition count: per-chunk hist of dst>>7 AND src>>7 ----------------
__global__ __launch_bounds__(256) void k_pcount(const int* __restrict__ src, const int* __restrict__ dst,
                                                int* __restrict__ pmat_d, int* __restrict__ pmat_s,
                                                int E, int NB) {
    __shared__ int hd[1024], hs[1024];
    for (int i = threadIdx.x; i < 1024; i += 256) { hd[i] = 0; hs[i] = 0; }
    __syncthreads();
    int b = blockIdx.x;
    int e0 = b * CH, e1 = min(e0 + CH, E);
    for (int e = e0 + threadIdx.x; e < e1; e += 256) {
        atomicAdd(&hd[dst[e] >> 7], 1);
        atomicAdd(&hs[src[e] >> 7], 1);
    }
    __syncthreads();
    for (int i = threadIdx.x; i < NB; i += 256) {
        pmat_d[(size_t)b * NB + i] = hd[i];
        pmat_s[(size_t)b * NB + i] = hs[i];
    }
}

// per-bucket totals + exclusive scan -> bbase (grid=2: 0=dst, 1=src)
__global__ __launch_bounds__(1024) void k_pscan1(const int* __restrict__ pmat_d, const int* __restrict__ pmat_s,
                                                 int* __restrict__ bbase_d, int* __restrict__ bbase_s,
                                                 int NB, int nblk) {
    const int* pmat = blockIdx.x ? pmat_s : pmat_d;
    int* bbase = blockIdx.x ? bbase_s : bbase_d;
    __shared__ int s[1024];
    int t = threadIdx.x;
    int tot = 0;
    if (t < NB) {
#pragma unroll 8
        for (int b = 0; b < nblk; b++) tot += pmat[(size_t)b * NB + t];
    }
    s[t] = (t < NB) ? tot : 0;
    __syncthreads();
    for (int d = 1; d < 1024; d <<= 1) {
        int x = (t >= d) ? s[t - d] : 0;
        __syncthreads();
        s[t] += x;
        __syncthreads();
    }
    if (t < NB) {
        bbase[t] = s[t] - tot;
        if (t == NB - 1) bbase[NB] = s[t];
    }
}

// per-(chunk,bucket) scatter offsets (grid = 2 * ceil(NB/256); even=dst, odd=src)
__global__ __launch_bounds__(256) void k_pscan2(const int* __restrict__ pmat_d, const int* __restrict__ pmat_s,
                                                const int* __restrict__ bbase_d, const int* __restrict__ bbase_s,
                                                int* __restrict__ omat_d, int* __restrict__ omat_s,
                                                int NB, int nblk) {
    int which = blockIdx.x & 1;
    int t = (blockIdx.x >> 1) * 256 + threadIdx.x;
    const int* pmat = which ? pmat_s : pmat_d;
    const int* bbase = which ? bbase_s : bbase_d;
    int* omat = which ? omat_s : omat_d;
    if (t >= NB) return;
    int run = bbase[t];
#pragma unroll 8
    for (int b = 0; b < nblk; b++) {
        size_t idx = (size_t)b * NB + t;
        omat[idx] = run;
        run += pmat[idx];
    }
}

// dual scatter: dst-records (src | dstlow<<17) and src-count bytes (srclow)
__global__ __launch_bounds__(256) void k_pscatter(const int* __restrict__ src, const int* __restrict__ dst,
                                                  const int* __restrict__ omat_d, const int* __restrict__ omat_s,
                                                  unsigned int* __restrict__ ebuf_d, unsigned char* __restrict__ ebuf_s,
                                                  int E, int NB) {
    __shared__ int cd[1024], cs[1024];
    int b = blockIdx.x;
    for (int i = threadIdx.x; i < NB; i += 256) {
        cd[i] = omat_d[(size_t)b * NB + i];
        cs[i] = omat_s[(size_t)b * NB + i];
    }
    __syncthreads();
    int e0 = b * CH, e1 = min(e0 + CH, E);
    for (int e = e0 + threadIdx.x; e < e1; e += 256) {
        int s_ = src[e], d_ = dst[e];
        int pd = atomicAdd(&cd[d_ >> 7], 1);
        ebuf_d[pd] = (unsigned)s_ | ((unsigned)(d_ & 127) << 17);
        int ps = atomicAdd(&cs[s_ >> 7], 1);
        ebuf_s[ps] = (unsigned char)(s_ & 127);
    }
}

// per-src-bucket histogram of srclow bytes -> srcn
__global__ __launch_bounds__(256) void k_bcount(const unsigned char* __restrict__ ebuf_s,
                                                const int* __restrict__ bbase_s,
                                                float* __restrict__ srcn, int N) {
    __shared__ int cnt[128];
    int k = blockIdx.x;
    if (threadIdx.x < 128) cnt[threadIdx.x] = 0;
    __syncthreads();
    int beg = bbase_s[k], end = bbase_s[k + 1];
    for (int i = beg + threadIdx.x; i < end; i += 256) atomicAdd(&cnt[ebuf_s[i]], 1);
    __syncthreads();
    if (threadIdx.x < 128) {
        int v = k * 128 + threadIdx.x;
        if (v < N) {
            int c = cnt[threadIdx.x];
            if (c < 1) c = 1;
            srcn[v] = rsqrtf((float)c);
        }
    }
}

// ---------------- weights: all three transposes in one launch ----------------
__global__ void k_wt3(const float* __restrict__ W0, const float* __restrict__ W1, const float* __restrict__ W2,
                      unsigned short* __restrict__ Wt0, unsigned short* __restrict__ Wt1,
                      unsigned short* __restrict__ Wt2) {
    int b = blockIdx.x;
    const float* W; unsigned short* Wt; int total, base;
    if (b < 64)      { W = W0; Wt = Wt0; total = 16384; base = b * 256; }
    else if (b < 128){ W = W1; Wt = Wt1; total = 16384; base = (b - 64) * 256; }
    else             { W = W2; Wt = Wt2; total = 2048;  base = (b - 128) * 256; }
    int i = base + threadIdx.x;
    if (i < total) {
        int Ncol = total >> 7;
        int c = i >> 7, k = i & 127;
        Wt[i] = (unsigned short)bfr(W[k * Ncol + c]);
    }
}

// ---------------- A0 = bf16(features * srcn) ----------------
__global__ void k_prep(const float* __restrict__ F, const float* __restrict__ srcn,
                       unsigned short* __restrict__ A0, int N) {
    int i = blockIdx.x * blockDim.x + threadIdx.x;
    if (i >= N * 16) return;
    int row = i >> 4;
    float s = srcn[row];
    const float4* p = (const float4*)(F + (size_t)i * 8);
    float4 a = p[0], b = p[1];
    uint4 o;
    o.x = bfpack(a.x * s, a.y * s);
    o.y = bfpack(a.z * s, a.w * s);
    o.z = bfpack(b.x * s, b.y * s);
    o.w = bfpack(b.z * s, b.w * s);
    *(uint4*)(A0 + (size_t)i * 8) = o;
}

// ---------------- MFMA GEMM (unchanged, verified) ----------------
template <int NT, int EPI>
__global__ __launch_bounds__(256) void k_gemm_mfma(const unsigned short* __restrict__ A,
                                                   const unsigned short* __restrict__ Wt,
                                                   const float* __restrict__ bias,
                                                   unsigned short* __restrict__ outb,
                                                   float* __restrict__ outf, int M) {
    __shared__ unsigned short As[64 * 128];
    __shared__ unsigned short Ws[NT * 16 * 128];
    int tx = threadIdx.x;
    int row0 = blockIdx.x * 64;
    for (int p = 0; p < NT; ++p) {
        int r = p * 16 + (tx >> 4);
        int c = tx & 15;
        int cs = c ^ (r & 7);
        *(uint4*)(&Ws[(r * 16 + cs) * 8]) = *(const uint4*)(Wt + (size_t)r * 128 + c * 8);
    }
    for (int p = 0; p < 4; ++p) {
        int r = p * 16 + (tx >> 4);
        int c = tx & 15;
        int cs = c ^ (r & 7);
        int gr = row0 + r;
        uint4 v = make_uint4(0u, 0u, 0u, 0u);
        if (gr < M) v = *(const uint4*)(A + (size_t)gr * 128 + c * 8);
        *(uint4*)(&As[(r * 16 + cs) * 8]) = v;
    }
    __syncthreads();

    int w = tx >> 6, l = tx & 63;
    int lr = l & 15, lg = l >> 4;
    f4v acc[NT];
#pragma unroll
    for (int nt = 0; nt < NT; ++nt) { acc[nt][0] = 0.f; acc[nt][1] = 0.f; acc[nt][2] = 0.f; acc[nt][3] = 0.f; }

    int ar = w * 16 + lr;
#pragma unroll
    for (int kk = 0; kk < 4; ++kk) {
        s8v af = *(const s8v*)(&As[(ar * 16 + ((kk * 4 + lg) ^ (ar & 7))) * 8]);
#pragma unroll
        for (int nt = 0; nt < NT; ++nt) {
            int br = nt * 16 + lr;
            s8v bf = *(const s8v*)(&Ws[(br * 16 + ((kk * 4 + lg) ^ (br & 7))) * 8]);
            acc[nt] = __builtin_amdgcn_mfma_f32_16x16x32_bf16(af, bf, acc[nt], 0, 0, 0);
        }
    }
#pragma unroll
    for (int nt = 0; nt < NT; ++nt) {
#pragma unroll
        for (int i = 0; i < 4; ++i) {
            int R = row0 + w * 16 + lg * 4 + i;
            if (R < M) {
                int col = nt * 16 + lr;
                float v = acc[nt][i];
                if (EPI == 0) {
                    outb[(size_t)R * 128 + col] = (unsigned short)bfr(v);
                } else {
                    v += bias[col];
                    v = 1.f / (1.f + __expf(-v)) + 1e-8f;
                    outf[(size_t)R * 16 + col] = v;
                }
            }
        }
    }
}

// ---------------- bucketed aggregation: FULL bucket per block ----------------
// counting-sort bucket records by dstlow once, then 16 groups x 16 lanes,
// 8 nodes per group. EPI 0: bf16(relu(sum*dstn+bias)*srcn); EPI 1: bf16(sum*dstn)
template <int EPI>
__global__ __launch_bounds__(256) void k_bagg(const unsigned short* __restrict__ hw,
                                              const unsigned int* __restrict__ ebuf,
                                              const int* __restrict__ bbase,
                                              const float* __restrict__ srcn,
                                              const float* __restrict__ bias,
                                              unsigned short* __restrict__ out, int N) {
    __shared__ unsigned int rec[4096];
    __shared__ unsigned int sorted[4096];
    __shared__ int cnt[128];
    __shared__ int wstart[129];
    __shared__ int wcur[128];
    int k = blockIdx.x;
    int tx = threadIdx.x;
    int ebeg = bbase[k];
    int ecnt = bbase[k + 1] - ebeg;
    if (ecnt > 4096) ecnt = 4096;   // Poisson mean 2046, never triggers
    if (tx < 128) cnt[tx] = 0;
    __syncthreads();
    for (int i = tx; i < ecnt; i += 256) {
        unsigned int r = ebuf[ebeg + i];
        rec[i] = r;
        atomicAdd(&cnt[(r >> 17) & 127], 1);
    }
    __syncthreads();
    // parallel inclusive scan of cnt -> wstart/wcur
    if (tx < 128) wcur[tx] = cnt[tx];
    __syncthreads();
    for (int d = 1; d < 128; d <<= 1) {
        int x = (tx < 128 && tx >= d) ? wcur[tx - d] : 0;
        __syncthreads();
        if (tx < 128) wcur[tx] += x;
        __syncthreads();
    }
    if (tx < 128) wstart[tx] = wcur[tx] - cnt[tx];
    if (tx == 127) wstart[128] = wcur[127];
    __syncthreads();
    if (tx < 128) wcur[tx] = wstart[tx];
    __syncthreads();
    for (int i = tx; i < ecnt; i += 256) {
        unsigned int r = rec[i];
        int dl = (r >> 17) & 127;
        int p = atomicAdd(&wcur[dl], 1);
        sorted[p] = r & 0x1FFFFu;
    }
    __syncthreads();

    int g = tx >> 4, sub = tx & 15;
#pragma unroll
    for (int rep = 0; rep < 8; rep++) {
        int j = g + rep * 16;              // groups cover 16 consecutive nodes per rep
        int v = k * 128 + j;
        if (v >= N) continue;
        int s0 = wstart[j], s1 = wstart[j + 1];
        int deg = s1 - s0;

        float a0 = 0.f, a1 = 0.f, a2 = 0.f, a3 = 0.f, a4 = 0.f, a5 = 0.f, a6 = 0.f, a7 = 0.f;
#define ACC8(V)                                                         \
        a0 += bflo(V.x); a1 += bfhi(V.x); a2 += bflo(V.y); a3 += bfhi(V.y); \
        a4 += bflo(V.z); a5 += bfhi(V.z); a6 += bflo(V.w); a7 += bfhi(V.w);
        int e = s0;
        for (; e + 4 <= s1; e += 4) {
            int x0 = sorted[e], x1 = sorted[e + 1], x2 = sorted[e + 2], x3 = sorted[e + 3];
            uint4 v0 = *(const uint4*)(hw + (size_t)x0 * 128 + sub * 8);
            uint4 v1 = *(const uint4*)(hw + (size_t)x1 * 128 + sub * 8);
            uint4 v2 = *(const uint4*)(hw + (size_t)x2 * 128 + sub * 8);
            uint4 v3 = *(const uint4*)(hw + (size_t)x3 * 128 + sub * 8);
            ACC8(v0) ACC8(v1) ACC8(v2) ACC8(v3)
        }
        for (; e < s1; ++e) {
            int x0 = sorted[e];
            uint4 v0 = *(const uint4*)(hw + (size_t)x0 * 128 + sub * 8);
            ACC8(v0)
        }
#undef ACC8
        int d = deg < 1 ? 1 : deg;
        float dn = rsqrtf((float)d);
        float o0 = a0 * dn, o1 = a1 * dn, o2 = a2 * dn, o3 = a3 * dn;
        float o4 = a4 * dn, o5 = a5 * dn, o6 = a6 * dn, o7 = a7 * dn;
        if (EPI == 0) {
            float4 b0 = *(const float4*)(bias + sub * 8);
            float4 b1 = *(const float4*)(bias + sub * 8 + 4);
            float sn = srcn[v];
            o0 = fmaxf(o0 + b0.x, 0.f) * sn; o1 = fmaxf(o1 + b0.y, 0.f) * sn;
            o2 = fmaxf(o2 + b0.z, 0.f) * sn; o3 = fmaxf(o3 + b0.w, 0.f) * sn;
            o4 = fmaxf(o4 + b1.x, 0.f) * sn; o5 = fmaxf(o5 + b1.y, 0.f) * sn;
            o6 = fmaxf(o6 + b1.z, 0.f) * sn; o7 = fmaxf(o7 + b1.w, 0.f) * sn;
        }
        uint4 o;
        o.x = bfpack(o0, o1); o.y = bfpack(o2, o3);
        o.z = bfpack(o4, o5); o.w = bfpack(o6, o7);
        *(uint4*)(out + (size_t)v * 128 + sub * 8) = o;
    }
}

extern "C" void kernel_launch(void* const* d_in, const int* in_sizes, int n_in,
                              void* d_out, int out_size, void* d_ws, size_t ws_size,
                              hipStream_t stream) {
    const float* features = (const float*)d_in[0];
    const int*   src      = (const int*)d_in[1];
    const int*   dst      = (const int*)d_in[2];
    const float* W0       = (const float*)d_in[3];
    const float* b0       = (const float*)d_in[4];
    const float* W1       = (const float*)d_in[5];
    const float* b1       = (const float*)d_in[6];
    const float* W2       = (const float*)d_in[7];
    const float* b2       = (const float*)d_in[8];
    float* out = (float*)d_out;

    const int N = in_sizes[0] / 128;
    const int E = in_sizes[1];
    const int NB = (N + 127) >> 7;            // 782 buckets
    const int nblk = (E + CH - 1) / CH;       // 196 partition chunks

    char* ws = (char*)d_ws;
    size_t off = 0;
    auto alloc = [&](size_t bytes) -> char* {
        char* p = ws + off;
        off += (bytes + 255) / 256 * 256;
        return p;
    };
    int* pmat_d  = (int*)alloc((size_t)nblk * NB * 4);
    int* pmat_s  = (int*)alloc((size_t)nblk * NB * 4);
    int* omat_d  = (int*)alloc((size_t)nblk * NB * 4);
    int* omat_s  = (int*)alloc((size_t)nblk * NB * 4);
    int* bbase_d = (int*)alloc((size_t)(NB + 1) * 4);
    int* bbase_s = (int*)alloc((size_t)(NB + 1) * 4);
    unsigned int*  ebuf_d = (unsigned int*)alloc((size_t)E * 4);
    unsigned char* ebuf_s = (unsigned char*)alloc((size_t)E);
    float* srcn  = (float*)alloc((size_t)N * 4);
    unsigned short* Wt0 = (unsigned short*)alloc(128 * 128 * 2);
    unsigned short* Wt1 = (unsigned short*)alloc(128 * 128 * 2);
    unsigned short* Wt2 = (unsigned short*)alloc(16 * 128 * 2);
    unsigned short* B1 = (unsigned short*)alloc((size_t)N * 128 * 2);
    unsigned short* B2 = (unsigned short*)alloc((size_t)N * 128 * 2);
    unsigned short* B3 = (unsigned short*)alloc((size_t)N * 128 * 2);
    (void)ws_size; (void)n_in; (void)out_size;

    // graph build (no global data atomics)
    k_pcount<<<nblk, 256, 0, stream>>>(src, dst, pmat_d, pmat_s, E, NB);
    k_pscan1<<<2, 1024, 0, stream>>>(pmat_d, pmat_s, bbase_d, bbase_s, NB, nblk);
    k_pscan2<<<2 * ((NB + 255) / 256), 256, 0, stream>>>(pmat_d, pmat_s, bbase_d, bbase_s, omat_d, omat_s, NB, nblk);
    k_pscatter<<<nblk, 256, 0, stream>>>(src, dst, omat_d, omat_s, ebuf_d, ebuf_s, E, NB);
    k_bcount<<<NB, 256, 0, stream>>>(ebuf_s, bbase_s, srcn, N);

    // weights + input prep
    k_wt3<<<136, 256, 0, stream>>>(W0, W1, W2, Wt0, Wt1, Wt2);
    k_prep<<<(N * 16 + BLK - 1) / BLK, BLK, 0, stream>>>(features, srcn, B1, N);

    int gb = (N + 63) / 64;

    // layer 0
    k_gemm_mfma<8, 0><<<gb, 256, 0, stream>>>(B1, Wt0, nullptr, B2, nullptr, N);
    k_bagg<0><<<NB, 256, 0, stream>>>(B2, ebuf_d, bbase_d, srcn, b0, B3, N);
    // layer 1
    k_gemm_mfma<8, 0><<<gb, 256, 0, stream>>>(B3, Wt1, nullptr, B2, nullptr, N);
    k_bagg<0><<<NB, 256, 0, stream>>>(B2, ebuf_d, bbase_d, srcn, b1, B1, N);
    // layer 2: aggregate first (linearity), then 128->16 GEMM with bias+sigmoid
    k_bagg<1><<<NB, 256, 0, stream>>>(B1, ebuf_d, bbase_d, nullptr, nullptr, B3, N);
    k_gemm_mfma<1, 1><<<gb, 256, 0, stream>>>(B3, Wt2, b2, nullptr, out, N);
}

// Round 5
// 351.684 us; speedup vs baseline: 1.6636x; 1.1555x over previous
//
#include <hip/hip_runtime.h>
#include <hip/hip_bf16.h>

// GCN 3-layer GraphConv, R5:
//  - bucket partition (as R4) -> k_sortcsr builds global sorted CSR ONCE
//    (coalesced writes; no global atomics); aggs no longer sort per-layer
//  - k_aggN: LDS-free 16-lane-group-per-node gather (high occupancy)
//  - layer 2: GEMM first (128->16), then 32B-row gather w/ fused bias+sigmoid
//  - layer-0 GEMM stages fp32 features directly (k_prep fused away)
//  - GEMMs via mfma_f32_16x16x32_bf16 (verified since R2)

constexpr int BLK = 256;
constexpr int CH = 8192;     // edges per partition chunk-block -> 196 blocks

typedef __attribute__((ext_vector_type(8))) short s8v;
typedef __attribute__((ext_vector_type(4))) float f4v;

__device__ __forceinline__ float bflo(unsigned int u) { return __uint_as_float(u << 16); }
__device__ __forceinline__ float bfhi(unsigned int u) { return __uint_as_float(u & 0xffff0000u); }
__device__ __forceinline__ unsigned int bfr(float f) {
    unsigned int u = __float_as_uint(f);
    return (u + 0x7fffu + ((u >> 16) & 1u)) >> 16;
}
__device__ __forceinline__ unsigned int bfpack(float lo, float hi) {
    unsigned int ul = __float_as_uint(lo), uh = __float_as_uint(hi);
    unsigned int rl = (ul + 0x7fffu + ((ul >> 16) & 1u)) >> 16;
    unsigned int rh = (uh + 0x7fffu + ((uh >> 16) & 1u)) & 0xffff0000u;
    return rl | rh;
}

// ---------------- dual partition count ----------------
__global__ __launch_bounds__(256) void k_pcount(const int* __restrict__ src, const int* __restrict__ dst,
                                                int* __restrict__ pmat_d, int* __restrict__ pmat_s,
                                                int E, int NB) {
    __shared__ int hd[1024], hs[1024];
    for (int i = threadIdx.x; i < 1024; i += 256) { hd[i] = 0; hs[i] = 0; }
    __syncthreads();
    int b = blockIdx.x;
    int e0 = b * CH, e1 = min(e0 + CH, E);
    for (int e = e0 + threadIdx.x; e < e1; e += 256) {
        atomicAdd(&hd[dst[e] >> 7], 1);
        atomicAdd(&hs[src[e] >> 7], 1);
    }
    __syncthreads();
    for (int i = threadIdx.x; i < NB; i += 256) {
        pmat_d[(size_t)b * NB + i] = hd[i];
        pmat_s[(size_t)b * NB + i] = hs[i];
    }
}

__global__ __launch_bounds__(1024) void k_pscan1(const int* __restrict__ pmat_d, const int* __restrict__ pmat_s,
                                                 int* __restrict__ bbase_d, int* __restrict__ bbase_s,
                                                 int NB, int nblk) {
    const int* pmat = blockIdx.x ? pmat_s : pmat_d;
    int* bbase = blockIdx.x ? bbase_s : bbase_d;
    __shared__ int s[1024];
    int t = threadIdx.x;
    int tot = 0;
    if (t < NB) {
#pragma unroll 8
        for (int b = 0; b < nblk; b++) tot += pmat[(size_t)b * NB + t];
    }
    s[t] = (t < NB) ? tot : 0;
    __syncthreads();
    for (int d = 1; d < 1024; d <<= 1) {
        int x = (t >= d) ? s[t - d] : 0;
        __syncthreads();
        s[t] += x;
        __syncthreads();
    }
    if (t < NB) {
        bbase[t] = s[t] - tot;
        if (t == NB - 1) bbase[NB] = s[t];
    }
}

__global__ __launch_bounds__(256) void k_pscan2(const int* __restrict__ pmat_d, const int* __restrict__ pmat_s,
                                                const int* __restrict__ bbase_d, const int* __restrict__ bbase_s,
                                                int* __restrict__ omat_d, int* __restrict__ omat_s,
                                                int NB, int nblk) {
    int which = blockIdx.x & 1;
    int t = (blockIdx.x >> 1) * 256 + threadIdx.x;
    const int* pmat = which ? pmat_s : pmat_d;
    const int* bbase = which ? bbase_s : bbase_d;
    int* omat = which ? omat_s : omat_d;
    if (t >= NB) return;
    int run = bbase[t];
#pragma unroll 8
    for (int b = 0; b < nblk; b++) {
        size_t idx = (size_t)b * NB + t;
        omat[idx] = run;
        run += pmat[idx];
    }
}

__global__ __launch_bounds__(256) void k_pscatter(const int* __restrict__ src, const int* __restrict__ dst,
                                                  const int* __restrict__ omat_d, const int* __restrict__ omat_s,
                                                  unsigned int* __restrict__ ebuf_d, unsigned char* __restrict__ ebuf_s,
                                                  int E, int NB) {
    __shared__ int cd[1024], cs[1024];
    int b = blockIdx.x;
    for (int i = threadIdx.x; i < NB; i += 256) {
        cd[i] = omat_d[(size_t)b * NB + i];
        cs[i] = omat_s[(size_t)b * NB + i];
    }
    __syncthreads();
    int e0 = b * CH, e1 = min(e0 + CH, E);
    for (int e = e0 + threadIdx.x; e < e1; e += 256) {
        int s_ = src[e], d_ = dst[e];
        int pd = atomicAdd(&cd[d_ >> 7], 1);
        ebuf_d[pd] = (unsigned)s_ | ((unsigned)(d_ & 127) << 17);
        int ps = atomicAdd(&cs[s_ >> 7], 1);
        ebuf_s[ps] = (unsigned char)(s_ & 127);
    }
}

// per-src-bucket histogram -> srcn
__global__ __launch_bounds__(256) void k_bcount(const unsigned char* __restrict__ ebuf_s,
                                                const int* __restrict__ bbase_s,
                                                float* __restrict__ srcn, int N) {
    __shared__ int cnt[128];
    int k = blockIdx.x;
    if (threadIdx.x < 128) cnt[threadIdx.x] = 0;
    __syncthreads();
    int beg = bbase_s[k], end = bbase_s[k + 1];
    for (int i = beg + threadIdx.x; i < end; i += 256) atomicAdd(&cnt[ebuf_s[i]], 1);
    __syncthreads();
    if (threadIdx.x < 128) {
        int v = k * 128 + threadIdx.x;
        if (v < N) {
            int c = cnt[threadIdx.x];
            if (c < 1) c = 1;
            srcn[v] = rsqrtf((float)c);
        }
    }
}

// ---------------- sort each dst-bucket ONCE -> global CSR ----------------
__global__ __launch_bounds__(256) void k_sortcsr(const unsigned int* __restrict__ ebuf,
                                                 const int* __restrict__ bbase,
                                                 int* __restrict__ csr, int* __restrict__ rowptr,
                                                 int N, int E) {
    __shared__ unsigned int rec[4096];
    __shared__ unsigned int sorted[4096];
    __shared__ int cnt[128];
    __shared__ int wstart[129];
    __shared__ int wcur[128];
    int k = blockIdx.x, tx = threadIdx.x;
    int ebeg = bbase[k];
    int ecnt = bbase[k + 1] - ebeg;
    if (ecnt > 4096) ecnt = 4096;   // Poisson mean ~2046; never triggers
    if (tx < 128) cnt[tx] = 0;
    __syncthreads();
    for (int i = tx; i < ecnt; i += 256) {
        unsigned int r = ebuf[ebeg + i];
        rec[i] = r;
        atomicAdd(&cnt[(r >> 17) & 127], 1);
    }
    __syncthreads();
    if (tx < 128) wcur[tx] = cnt[tx];
    __syncthreads();
    for (int d = 1; d < 128; d <<= 1) {
        int x = (tx < 128 && tx >= d) ? wcur[tx - d] : 0;
        __syncthreads();
        if (tx < 128) wcur[tx] += x;
        __syncthreads();
    }
    if (tx < 128) wstart[tx] = wcur[tx] - cnt[tx];
    if (tx == 127) wstart[128] = wcur[127];
    __syncthreads();
    if (tx < 128) wcur[tx] = wstart[tx];
    __syncthreads();
    for (int i = tx; i < ecnt; i += 256) {
        unsigned int r = rec[i];
        int p = atomicAdd(&wcur[(r >> 17) & 127], 1);
        sorted[p] = r & 0x1FFFFu;
    }
    __syncthreads();
    for (int i = tx; i < ecnt; i += 256) csr[ebeg + i] = (int)sorted[i];
    if (tx < 128) {
        int v = k * 128 + tx;
        if (v < N) rowptr[v] = ebeg + wstart[tx];
    }
    if (k == (int)gridDim.x - 1 && tx == 0) rowptr[N] = E;
}

// ---------------- weights: all three transposes in one launch ----------------
__global__ void k_wt3(const float* __restrict__ W0, const float* __restrict__ W1, const float* __restrict__ W2,
                      unsigned short* __restrict__ Wt0, unsigned short* __restrict__ Wt1,
                      unsigned short* __restrict__ Wt2) {
    int b = blockIdx.x;
    const float* W; unsigned short* Wt; int total, base;
    if (b < 64)      { W = W0; Wt = Wt0; total = 16384; base = b * 256; }
    else if (b < 128){ W = W1; Wt = Wt1; total = 16384; base = (b - 64) * 256; }
    else             { W = W2; Wt = Wt2; total = 2048;  base = (b - 128) * 256; }
    int i = base + threadIdx.x;
    if (i < total) {
        int Ncol = total >> 7;
        int c = i >> 7, k = i & 127;
        Wt[i] = (unsigned short)bfr(W[k * Ncol + c]);
    }
}

// ---------------- MFMA GEMM: out[M x NT*16] = A[M x 128] @ Wt^T (bf16 store) ----------------
// F32IN: A is fp32, scaled by srcn during staging (layer 0; k_prep fused)
template <int NT, int F32IN>
__global__ __launch_bounds__(256) void k_gemm_mfma(const unsigned short* __restrict__ Ab,
                                                   const float* __restrict__ Af,
                                                   const float* __restrict__ srcn,
                                                   const unsigned short* __restrict__ Wt,
                                                   unsigned short* __restrict__ outb, int M) {
    __shared__ unsigned short As[64 * 128];
    __shared__ unsigned short Ws[NT * 16 * 128];
    int tx = threadIdx.x;
    int row0 = blockIdx.x * 64;
    for (int p = 0; p < NT; ++p) {
        int r = p * 16 + (tx >> 4);
        int c = tx & 15;
        int cs = c ^ (r & 7);
        *(uint4*)(&Ws[(r * 16 + cs) * 8]) = *(const uint4*)(Wt + (size_t)r * 128 + c * 8);
    }
    for (int p = 0; p < 4; ++p) {
        int r = p * 16 + (tx >> 4);
        int c = tx & 15;
        int cs = c ^ (r & 7);
        int gr = row0 + r;
        uint4 v = make_uint4(0u, 0u, 0u, 0u);
        if (gr < M) {
            if (F32IN) {
                const float4* pf = (const float4*)(Af + (size_t)gr * 128 + c * 8);
                float4 a = pf[0], b = pf[1];
                float s = srcn[gr];
                v.x = bfpack(a.x * s, a.y * s);
                v.y = bfpack(a.z * s, a.w * s);
                v.z = bfpack(b.x * s, b.y * s);
                v.w = bfpack(b.z * s, b.w * s);
            } else {
                v = *(const uint4*)(Ab + (size_t)gr * 128 + c * 8);
            }
        }
        *(uint4*)(&As[(r * 16 + cs) * 8]) = v;
    }
    __syncthreads();

    int w = tx >> 6, l = tx & 63;
    int lr = l & 15, lg = l >> 4;
    f4v acc[NT];
#pragma unroll
    for (int nt = 0; nt < NT; ++nt) { acc[nt][0] = 0.f; acc[nt][1] = 0.f; acc[nt][2] = 0.f; acc[nt][3] = 0.f; }

    int ar = w * 16 + lr;
#pragma unroll
    for (int kk = 0; kk < 4; ++kk) {
        s8v af = *(const s8v*)(&As[(ar * 16 + ((kk * 4 + lg) ^ (ar & 7))) * 8]);
#pragma unroll
        for (int nt = 0; nt < NT; ++nt) {
            int br = nt * 16 + lr;
            s8v bf = *(const s8v*)(&Ws[(br * 16 + ((kk * 4 + lg) ^ (br & 7))) * 8]);
            acc[nt] = __builtin_amdgcn_mfma_f32_16x16x32_bf16(af, bf, acc[nt], 0, 0, 0);
        }
    }
#pragma unroll
    for (int nt = 0; nt < NT; ++nt) {
#pragma unroll
        for (int i = 0; i < 4; ++i) {
            int R = row0 + w * 16 + lg * 4 + i;
            if (R < M) {
                int col = nt * 16 + lr;
                outb[(size_t)R * (NT * 16) + col] = (unsigned short)bfr(acc[nt][i]);
            }
        }
    }
}

// ---------------- agg 128-wide: LDS-free, 16-lane group per node ----------------
// out = bf16(relu(sum*dstn + bias) * srcn)   (dstn from rowptr degree)
__global__ __launch_bounds__(256) void k_aggN(const unsigned short* __restrict__ hw,
                                              const int* __restrict__ csr,
                                              const int* __restrict__ rowptr,
                                              const float* __restrict__ srcn,
                                              const float* __restrict__ bias,
                                              unsigned short* __restrict__ out, int N) {
    int t = blockIdx.x * 256 + threadIdx.x;
    int v = t >> 4, sub = t & 15;
    if (v >= N) return;
    int s0 = rowptr[v], s1 = rowptr[v + 1];

    float a0 = 0.f, a1 = 0.f, a2 = 0.f, a3 = 0.f, a4 = 0.f, a5 = 0.f, a6 = 0.f, a7 = 0.f;
#define ACC8(V)                                                         \
    a0 += bflo(V.x); a1 += bfhi(V.x); a2 += bflo(V.y); a3 += bfhi(V.y); \
    a4 += bflo(V.z); a5 += bfhi(V.z); a6 += bflo(V.w); a7 += bfhi(V.w);
    int e = s0;
    for (; e + 4 <= s1; e += 4) {
        int x0 = csr[e], x1 = csr[e + 1], x2 = csr[e + 2], x3 = csr[e + 3];
        uint4 v0 = *(const uint4*)(hw + (size_t)x0 * 128 + sub * 8);
        uint4 v1 = *(const uint4*)(hw + (size_t)x1 * 128 + sub * 8);
        uint4 v2 = *(const uint4*)(hw + (size_t)x2 * 128 + sub * 8);
        uint4 v3 = *(const uint4*)(hw + (size_t)x3 * 128 + sub * 8);
        ACC8(v0) ACC8(v1) ACC8(v2) ACC8(v3)
    }
    for (; e < s1; ++e) {
        int x0 = csr[e];
        uint4 v0 = *(const uint4*)(hw + (size_t)x0 * 128 + sub * 8);
        ACC8(v0)
    }
#undef ACC8
    int deg = s1 - s0;
    if (deg < 1) deg = 1;
    float dn = rsqrtf((float)deg);
    float4 b0 = *(const float4*)(bias + sub * 8);
    float4 b1 = *(const float4*)(bias + sub * 8 + 4);
    float sn = srcn[v];
    float o0 = fmaxf(a0 * dn + b0.x, 0.f) * sn, o1 = fmaxf(a1 * dn + b0.y, 0.f) * sn;
    float o2 = fmaxf(a2 * dn + b0.z, 0.f) * sn, o3 = fmaxf(a3 * dn + b0.w, 0.f) * sn;
    float o4 = fmaxf(a4 * dn + b1.x, 0.f) * sn, o5 = fmaxf(a5 * dn + b1.y, 0.f) * sn;
    float o6 = fmaxf(a6 * dn + b1.z, 0.f) * sn, o7 = fmaxf(a7 * dn + b1.w, 0.f) * sn;
    uint4 o;
    o.x = bfpack(o0, o1); o.y = bfpack(o2, o3);
    o.z = bfpack(o4, o5); o.w = bfpack(o6, o7);
    *(uint4*)(out + (size_t)v * 128 + sub * 8) = o;
}

// ---------------- agg 16-wide (layer 2): 4-lane group per node, fused bias+sigmoid ----------------
__global__ __launch_bounds__(256) void k_agg16(const unsigned short* __restrict__ hw,
                                               const int* __restrict__ csr,
                                               const int* __restrict__ rowptr,
                                               const float* __restrict__ bias,
                                               float* __restrict__ out, int N) {
    int t = blockIdx.x * 256 + threadIdx.x;
    int v = t >> 2, q = t & 3;
    if (v >= N) return;
    int s0 = rowptr[v], s1 = rowptr[v + 1];
    float a0 = 0.f, a1 = 0.f, a2 = 0.f, a3 = 0.f;
#define ACC4(V)                                                         \
    a0 += bflo(V.x); a1 += bfhi(V.x); a2 += bflo(V.y); a3 += bfhi(V.y);
    int e = s0;
    for (; e + 4 <= s1; e += 4) {
        int x0 = csr[e], x1 = csr[e + 1], x2 = csr[e + 2], x3 = csr[e + 3];
        uint2 v0 = *(const uint2*)(hw + (size_t)x0 * 16 + q * 4);
        uint2 v1 = *(const uint2*)(hw + (size_t)x1 * 16 + q * 4);
        uint2 v2 = *(const uint2*)(hw + (size_t)x2 * 16 + q * 4);
        uint2 v3 = *(const uint2*)(hw + (size_t)x3 * 16 + q * 4);
        ACC4(v0) ACC4(v1) ACC4(v2) ACC4(v3)
    }
    for (; e < s1; ++e) {
        int x0 = csr[e];
        uint2 v0 = *(const uint2*)(hw + (size_t)x0 * 16 + q * 4);
        ACC4(v0)
    }
#undef ACC4
    int deg = s1 - s0;
    if (deg < 1) deg = 1;
    float dn = rsqrtf((float)deg);
    float4 b = *(const float4*)(bias + q * 4);
    float o0 = 1.f / (1.f + __expf(-(a0 * dn + b.x))) + 1e-8f;
    float o1 = 1.f / (1.f + __expf(-(a1 * dn + b.y))) + 1e-8f;
    float o2 = 1.f / (1.f + __expf(-(a2 * dn + b.z))) + 1e-8f;
    float o3 = 1.f / (1.f + __expf(-(a3 * dn + b.w))) + 1e-8f;
    *(float4*)(out + (size_t)v * 16 + q * 4) = make_float4(o0, o1, o2, o3);
}

extern "C" void kernel_launch(void* const* d_in, const int* in_sizes, int n_in,
                              void* d_out, int out_size, void* d_ws, size_t ws_size,
                              hipStream_t stream) {
    const float* features = (const float*)d_in[0];
    const int*   src      = (const int*)d_in[1];
    const int*   dst      = (const int*)d_in[2];
    const float* W0       = (const float*)d_in[3];
    const float* b0       = (const float*)d_in[4];
    const float* W1       = (const float*)d_in[5];
    const float* b1       = (const float*)d_in[6];
    const float* W2       = (const float*)d_in[7];
    const float* b2       = (const float*)d_in[8];
    float* out = (float*)d_out;

    const int N = in_sizes[0] / 128;
    const int E = in_sizes[1];
    const int NB = (N + 127) >> 7;            // 782 buckets
    const int nblk = (E + CH - 1) / CH;       // 196 partition chunks

    char* ws = (char*)d_ws;
    size_t off = 0;
    auto alloc = [&](size_t bytes) -> char* {
        char* p = ws + off;
        off += (bytes + 255) / 256 * 256;
        return p;
    };
    int* pmat_d  = (int*)alloc((size_t)nblk * NB * 4);
    int* pmat_s  = (int*)alloc((size_t)nblk * NB * 4);
    int* omat_d  = (int*)alloc((size_t)nblk * NB * 4);
    int* omat_s  = (int*)alloc((size_t)nblk * NB * 4);
    int* bbase_d = (int*)alloc((size_t)(NB + 1) * 4);
    int* bbase_s = (int*)alloc((size_t)(NB + 1) * 4);
    unsigned int*  ebuf_d = (unsigned int*)alloc((size_t)E * 4);
    unsigned char* ebuf_s = (unsigned char*)alloc((size_t)E);
    int* csr     = (int*)alloc((size_t)E * 4);
    int* rowptr  = (int*)alloc((size_t)(N + 1) * 4);
    float* srcn  = (float*)alloc((size_t)N * 4);
    unsigned short* Wt0 = (unsigned short*)alloc(128 * 128 * 2);
    unsigned short* Wt1 = (unsigned short*)alloc(128 * 128 * 2);
    unsigned short* Wt2 = (unsigned short*)alloc(16 * 128 * 2);
    unsigned short* B1 = (unsigned short*)alloc((size_t)N * 128 * 2);
    unsigned short* B2 = (unsigned short*)alloc((size_t)N * 128 * 2);
    unsigned short* HW16 = (unsigned short*)alloc((size_t)N * 16 * 2);
    (void)ws_size; (void)n_in; (void)out_size;

    // graph build
    k_pcount<<<nblk, 256, 0, stream>>>(src, dst, pmat_d, pmat_s, E, NB);
    k_pscan1<<<2, 1024, 0, stream>>>(pmat_d, pmat_s, bbase_d, bbase_s, NB, nblk);
    k_pscan2<<<2 * ((NB + 255) / 256), 256, 0, stream>>>(pmat_d, pmat_s, bbase_d, bbase_s, omat_d, omat_s, NB, nblk);
    k_pscatter<<<nblk, 256, 0, stream>>>(src, dst, omat_d, omat_s, ebuf_d, ebuf_s, E, NB);
    k_bcount<<<NB, 256, 0, stream>>>(ebuf_s, bbase_s, srcn, N);
    k_sortcsr<<<NB, 256, 0, stream>>>(ebuf_d, bbase_d, csr, rowptr, N, E);
    k_wt3<<<136, 256, 0, stream>>>(W0, W1, W2, Wt0, Wt1, Wt2);

    int gb = (N + 63) / 64;
    int anb = (N * 16 + 255) / 256;
    int a16b = (N * 4 + 255) / 256;

    // layer 0 (fp32 features staged + scaled in-GEMM)
    k_gemm_mfma<8, 1><<<gb, 256, 0, stream>>>(nullptr, features, srcn, Wt0, B2, N);
    k_aggN<<<anb, 256, 0, stream>>>(B2, csr, rowptr, srcn, b0, B1, N);
    // layer 1
    k_gemm_mfma<8, 0><<<gb, 256, 0, stream>>>(B1, nullptr, nullptr, Wt1, B2, N);
    k_aggN<<<anb, 256, 0, stream>>>(B2, csr, rowptr, srcn, b1, B1, N);
    // layer 2: GEMM to 16-wide first, then cheap 32B-row gather w/ bias+sigmoid
    k_gemm_mfma<1, 0><<<gb, 256, 0, stream>>>(B1, nullptr, nullptr, Wt2, HW16, N);
    k_agg16<<<a16b, 256, 0, stream>>>(HW16, csr, rowptr, b2, out, N);
}